// Round 1
// baseline (691.395 us; speedup 1.0000x reference)
//
#include <hip/hip_runtime.h>

#define NROWS 512
#define KD    512
#define NCLS  100000
#define BC    64
#define S_SCALE 64.0f
#define COS_M   0.87758256189037276f
#define SIN_M   0.47942553860420301f
#define THRESH (-0.87758256189037276f)
#define MM_C    0.23971276930210151f

typedef __attribute__((ext_vector_type(8))) short short8;
typedef __attribute__((ext_vector_type(4))) float f32x4;

union Pack8 { unsigned short u[8]; uint4 v; };

__device__ __forceinline__ unsigned short f2bf(float x) {
  unsigned int u = __float_as_uint(x);
  u += 0x7fffu + ((u >> 16) & 1u);   // round-to-nearest-even
  return (unsigned short)(u >> 16);
}

// ---------------- K0: row-normalize embeddings -> e32 (fp32) + eb (bf16) ----
__global__ void k_norm_e(const float* __restrict__ emb, float* __restrict__ e32,
                         unsigned short* __restrict__ eb) {
  int r = blockIdx.x;
  int l = threadIdx.x;                 // 64 lanes, 8 elems each
  const float* src = emb + (size_t)r * KD + l * 8;
  float v[8];
  float ss = 0.f;
#pragma unroll
  for (int j = 0; j < 8; ++j) { v[j] = src[j]; ss += v[j] * v[j]; }
#pragma unroll
  for (int m = 1; m < 64; m <<= 1) ss += __shfl_xor(ss, m, 64);
  float rn = rsqrtf(ss);
  float* d32 = e32 + (size_t)r * KD + l * 8;
  unsigned short* db = eb + (size_t)r * KD + l * 8;
#pragma unroll
  for (int j = 0; j < 8; ++j) {
    float x = v[j] * rn;
    d32[j] = x;
    db[j] = f2bf(x);
  }
}

// ---------------- K1: per-row target logit (fp32, own column norm); zero gsums
__global__ void k_target(const float* __restrict__ e32, const float* __restrict__ w,
                         const int* __restrict__ label, float* __restrict__ tlA,
                         float* __restrict__ gsumE, float* __restrict__ gsumL) {
  int r = blockIdx.x;
  int l = threadIdx.x;                 // 64 lanes
  int lab = label[r];
  float dot = 0.f, sq = 0.f;
#pragma unroll
  for (int it = 0; it < 8; ++it) {
    int k = l + it * 64;
    float wv = w[(size_t)k * NCLS + lab];
    dot += e32[(size_t)r * KD + k] * wv;
    sq  += wv * wv;
  }
#pragma unroll
  for (int m = 1; m < 64; m <<= 1) {
    dot += __shfl_xor(dot, m, 64);
    sq  += __shfl_xor(sq, m, 64);
  }
  if (l == 0) {
    float tl = dot * rsqrtf(sq);
    tl = fminf(1.f, fmaxf(-1.f, tl));
    tlA[r] = tl;
    gsumE[r] = 0.f;
    gsumL[r] = 0.f;
  }
}

// ---------------- K2: t = 0.01*mean(tl); per-row ctm / final ----------------
__global__ void k_prep(const float* __restrict__ tlA, float* __restrict__ ctmA,
                       float* __restrict__ finA, float* __restrict__ tval) {
  __shared__ float red[512];
  int i = threadIdx.x;
  float tl = tlA[i];
  red[i] = tl;
  __syncthreads();
  for (int s = 256; s > 0; s >>= 1) {
    if (i < s) red[i] += red[i + s];
    __syncthreads();
  }
  float st = sqrtf(fmaxf(0.f, 1.f - tl * tl));
  float ctm = tl * COS_M - st * SIN_M;
  ctmA[i] = ctm;
  finA[i] = (tl > THRESH) ? ctm : (tl - MM_C);
  if (i == 0) tval[0] = 0.01f * red[0] * (1.f / 512.f);
}

// ---------------- K3: fused norm + bf16 MFMA GEMM + logit transform + row sums
// Block: 512 rows x 64 cols, K=512.  LDS: 64KB swizzled bf16 B-tile [c][k],
// granule G = c*64 + (k8 ^ (c&7)); element byte = G*16 + (k&7)*2.
__global__ __launch_bounds__(256, 2)
void k_gemm(const float* __restrict__ w, const unsigned short* __restrict__ eb,
            const int* __restrict__ label, const float* __restrict__ ctmA,
            const float* __restrict__ finA, const float* __restrict__ tval,
            float* __restrict__ gsumE, float* __restrict__ gsumL) {
  __shared__ __align__(16) unsigned short Bs[BC * KD];   // 65536 B
  const int tid = threadIdx.x;
  const int wv = tid >> 6;             // wave 0..3
  const int l  = tid & 63;
  const int c0 = blockIdx.x * BC;

  // ---- staging: wave wv owns cols [wv*16, wv*16+16), full K ----
  {
    const int c  = wv * 16 + (l >> 2);       // block-local col
    const int cg = c0 + c;
    const bool cv = (cg < NCLS);
    const int kq = l & 3;                    // k-slot within 32-chunk
    float ss = 0.f;
#pragma unroll 4
    for (int o = 0; o < 16; ++o) {
      Pack8 p;
      int kb = o * 32 + kq * 8;
#pragma unroll
      for (int j = 0; j < 8; ++j) {
        float v = cv ? w[(size_t)(kb + j) * NCLS + cg] : 0.f;
        ss += v * v;
        p.u[j] = f2bf(v);
      }
      int G = c * 64 + ((kb >> 3) ^ (c & 7));
      *reinterpret_cast<uint4*>(&Bs[G * 8]) = p.v;
    }
    // full-column sumsq: reduce over the 4 k-slots (lanes xor 1,2)
    ss += __shfl_xor(ss, 1, 64);
    ss += __shfl_xor(ss, 2, 64);
    float invn = (ss > 0.f) ? rsqrtf(ss) : 0.f;
    // in-place rescale of this thread's own granules (no sync needed)
#pragma unroll 4
    for (int o = 0; o < 16; ++o) {
      int kb = o * 32 + kq * 8;
      int G = c * 64 + ((kb >> 3) ^ (c & 7));
      Pack8 p;
      p.v = *reinterpret_cast<uint4*>(&Bs[G * 8]);
#pragma unroll
      for (int j = 0; j < 8; ++j) {
        float v = __uint_as_float(((unsigned int)p.u[j]) << 16);
        p.u[j] = f2bf(v * invn);
      }
      *reinterpret_cast<uint4*>(&Bs[G * 8]) = p.v;
    }
  }
  __syncthreads();

  // ---- MFMA main loop: wave tile = 128 rows x 64 cols ----
  const int q  = l >> 4;
  const int cl = l & 15;
  const int rbase = wv * 128;
  f32x4 acc[8][4] = {};

#pragma unroll 1
  for (int s = 0; s < 16; ++s) {
    const int k0 = s * 32 + q * 8;
    short8 a[8], b[4];
#pragma unroll
    for (int ct = 0; ct < 4; ++ct) {
      int c = ct * 16 + cl;
      int G = c * 64 + ((k0 >> 3) ^ (c & 7));
      b[ct] = *reinterpret_cast<const short8*>(&Bs[G * 8]);
    }
#pragma unroll
    for (int rt = 0; rt < 8; ++rt) {
      int row = rbase + rt * 16 + cl;
      a[rt] = *reinterpret_cast<const short8*>(eb + (size_t)row * KD + k0);
    }
#pragma unroll
    for (int rt = 0; rt < 8; ++rt)
#pragma unroll
      for (int ct = 0; ct < 4; ++ct)
        acc[rt][ct] = __builtin_amdgcn_mfma_f32_16x16x32_bf16(a[rt], b[ct], acc[rt][ct], 0, 0, 0);
  }

  // ---- epilogue: transform + per-row sum(exp) / sum(logit), atomics ----
  const float t = tval[0];
#pragma unroll 1
  for (int rt = 0; rt < 8; ++rt) {
    int rowb = rbase + rt * 16 + q * 4;
#pragma unroll
    for (int rg = 0; rg < 4; ++rg) {
      int row = rowb + rg;
      float ctm = ctmA[row];
      float fin = finA[row];
      int   lab = label[row];
      float se = 0.f, sl = 0.f;
#pragma unroll
      for (int ct = 0; ct < 4; ++ct) {
        int cg = c0 + ct * 16 + cl;
        if (cg < NCLS) {
          float cosv = acc[rt][ct][rg];        // inv_norm already folded into B
          cosv = fminf(1.f, fmaxf(-1.f, cosv));
          float logit = (cosv > ctm) ? cosv * (t + cosv) : cosv;
          if (cg == lab) logit = fin;
          float x = S_SCALE * logit;
          se += __expf(x);
          sl += x;
        }
      }
#pragma unroll
      for (int m = 1; m < 16; m <<= 1) {
        se += __shfl_xor(se, m, 64);
        sl += __shfl_xor(sl, m, 64);
      }
      if (cl == 0) {
        atomicAdd(&gsumE[row], se);
        atomicAdd(&gsumL[row], sl);
      }
    }
  }
}

// ---------------- K4: final loss ----------------
__global__ void k_loss(const float* __restrict__ gsumE, const float* __restrict__ gsumL,
                       const float* __restrict__ finA, float* __restrict__ out) {
  __shared__ float red[512];
  int i = threadIdx.x;
  float P = gsumE[i];
  float Q = gsumL[i];
  float lse = logf(P);                         // no max-shift needed: P < 1e34
  float nll = lse - S_SCALE * finA[i];
  float sm  = lse - Q * (1.f / (float)NCLS);
  red[i] = 0.9f * nll + 0.1f * sm;
  __syncthreads();
  for (int s = 256; s > 0; s >>= 1) {
    if (i < s) red[i] += red[i + s];
    __syncthreads();
  }
  if (i == 0) out[0] = red[0] * (1.f / 512.f);
}

extern "C" void kernel_launch(void* const* d_in, const int* in_sizes, int n_in,
                              void* d_out, int out_size, void* d_ws, size_t ws_size,
                              hipStream_t stream) {
  (void)in_sizes; (void)n_in; (void)out_size; (void)ws_size;
  const float* emb = (const float*)d_in[0];
  const float* w   = (const float*)d_in[1];
  const int*   lab = (const int*)d_in[2];
  float* out = (float*)d_out;

  char* ws = (char*)d_ws;
  float* e32 = (float*)ws;                                        // 512*512 fp32 (1 MB)
  unsigned short* eb = (unsigned short*)(ws + 512 * 512 * 4);     // 512*512 bf16 (512 KB)
  float* tlA   = (float*)(ws + 512 * 512 * 4 + 512 * 512 * 2);
  float* ctmA  = tlA   + 512;
  float* finA  = ctmA  + 512;
  float* gsumE = finA  + 512;
  float* gsumL = gsumE + 512;
  float* tval  = gsumL + 512;

  hipLaunchKernelGGL(k_norm_e, dim3(512), dim3(64), 0, stream, emb, e32, eb);
  hipLaunchKernelGGL(k_target, dim3(512), dim3(64), 0, stream, e32, w, lab, tlA, gsumE, gsumL);
  hipLaunchKernelGGL(k_prep,   dim3(1),   dim3(512), 0, stream, tlA, ctmA, finA, tval);
  hipLaunchKernelGGL(k_gemm,   dim3((NCLS + BC - 1) / BC), dim3(256), 0, stream,
                     w, eb, lab, ctmA, finA, tval, gsumE, gsumL);
  hipLaunchKernelGGL(k_loss,   dim3(1),   dim3(512), 0, stream, gsumE, gsumL, finA, out);
}

// Round 2
// 589.755 us; speedup vs baseline: 1.1723x; 1.1723x over previous
//
#include <hip/hip_runtime.h>

#define KD    512
#define NCLS  100000
#define BC    64
#define NB    ((NCLS + BC - 1) / BC)   // 1563
#define NBPAD 1600
#define S_SCALE 64.0f
#define COS_M   0.87758256189037276f
#define SIN_M   0.47942553860420301f
#define THRESH (-0.87758256189037276f)
#define MM_C    0.23971276930210151f

typedef __attribute__((ext_vector_type(8))) short short8;
typedef __attribute__((ext_vector_type(4))) float f32x4;

union Pack8 { unsigned short u[8]; uint4 v; };

__device__ __forceinline__ unsigned short f2bf(float x) {
  unsigned int u = __float_as_uint(x);
  u += 0x7fffu + ((u >> 16) & 1u);   // round-to-nearest-even
  return (unsigned short)(u >> 16);
}

// ---- K0: fused row-normalize(e) -> eb bf16, plus per-row target logit ------
__global__ void k0_norm_target(const float* __restrict__ emb, const float* __restrict__ w,
                               const int* __restrict__ label,
                               unsigned short* __restrict__ eb, float* __restrict__ tlA) {
  int r = blockIdx.x;
  int l = threadIdx.x;                 // 64 lanes, 8 elems each
  const float* src = emb + (size_t)r * KD + l * 8;
  float v[8];
  float ss = 0.f;
#pragma unroll
  for (int j = 0; j < 8; ++j) { v[j] = src[j]; ss += v[j] * v[j]; }
#pragma unroll
  for (int m = 1; m < 64; m <<= 1) ss += __shfl_xor(ss, m, 64);
  float rn = rsqrtf(ss);
  Pack8 p;
#pragma unroll
  for (int j = 0; j < 8; ++j) {
    float x = v[j] * rn;
    v[j] = x;                          // normalized fp32 kept in regs
    p.u[j] = f2bf(x);
  }
  *reinterpret_cast<uint4*>(eb + (size_t)r * KD + l * 8) = p.v;

  // target-column dot + its own norm (fp32 path, matches reference gather)
  int lab = label[r];
  float dot = 0.f, sq = 0.f;
#pragma unroll
  for (int j = 0; j < 8; ++j) {
    float wv = w[(size_t)(l * 8 + j) * NCLS + lab];
    dot += v[j] * wv;
    sq  += wv * wv;
  }
#pragma unroll
  for (int m = 1; m < 64; m <<= 1) {
    dot += __shfl_xor(dot, m, 64);
    sq  += __shfl_xor(sq, m, 64);
  }
  if (l == 0) {
    float tl = dot * rsqrtf(sq);
    tlA[r] = fminf(1.f, fmaxf(-1.f, tl));
  }
}

// ---- K1: t = 0.01*mean(tl); per-row ctm / final; zero the output scalar ----
__global__ void k_prep(const float* __restrict__ tlA, float* __restrict__ ctmA,
                       float* __restrict__ finA, float* __restrict__ tval,
                       float* __restrict__ out) {
  __shared__ float red[512];
  int i = threadIdx.x;
  float tl = tlA[i];
  red[i] = tl;
  __syncthreads();
  for (int s = 256; s > 0; s >>= 1) {
    if (i < s) red[i] += red[i + s];
    __syncthreads();
  }
  float st = sqrtf(fmaxf(0.f, 1.f - tl * tl));
  float ctm = tl * COS_M - st * SIN_M;
  ctmA[i] = ctm;
  finA[i] = (tl > THRESH) ? ctm : (tl - MM_C);
  if (i == 0) { tval[0] = 0.01f * red[0] * (1.f / 512.f); out[0] = 0.f; }
}

// ---- K2: bf16 MFMA GEMM (raw w) + epilogue colnorm + row partial sums ------
// Block: 512 rows x 64 cols, K=512. Staging coalesced along c (col = lane).
// LDS B-tile [c][k] swizzled: granule G = c*64 + ((k>>3) ^ (c&7)), 8 bf16/granule.
__global__ __launch_bounds__(256, 2)
void k_gemm(const float* __restrict__ w, const unsigned short* __restrict__ eb,
            const int* __restrict__ label, const float* __restrict__ ctmA,
            const float* __restrict__ finA, const float* __restrict__ tval,
            float* __restrict__ partE, float* __restrict__ partL) {
  __shared__ __align__(16) unsigned short Bs[BC * KD];   // 64 KB
  __shared__ float ssW[4][BC];
  __shared__ float invnS[BC];
  const int tid = threadIdx.x;
  const int wv = tid >> 6;             // wave 0..3
  const int l  = tid & 63;
  const int c0 = blockIdx.x * BC;

  // ---- staging: col = lane (coalesced 256B per wave-load); wave wv covers
  //      k in {wv*8 + o*32 + j : o=0..15, j=0..7}  (8 consecutive k per granule)
  {
    const int c = l;
    const int cgc = (c0 + c < NCLS) ? (c0 + c) : (NCLS - 1);   // clamp, no OOB
    const float* wp = w + cgc;
    float ss = 0.f;
#pragma unroll 2
    for (int o = 0; o < 16; ++o) {
      const int kb = wv * 8 + o * 32;
      float v[8];
#pragma unroll
      for (int j = 0; j < 8; ++j) v[j] = wp[(size_t)(kb + j) * NCLS];
      Pack8 p;
#pragma unroll
      for (int j = 0; j < 8; ++j) { ss += v[j] * v[j]; p.u[j] = f2bf(v[j]); }
      const int G = c * 64 + ((kb >> 3) ^ (c & 7));
      *reinterpret_cast<uint4*>(&Bs[G * 8]) = p.v;
    }
    ssW[wv][c] = ss;
  }
  __syncthreads();
  if (tid < BC) {
    float s = ssW[0][tid] + ssW[1][tid] + ssW[2][tid] + ssW[3][tid];
    invnS[tid] = (s > 0.f) ? rsqrtf(s) : 0.f;
  }
  __syncthreads();

  // ---- MFMA main loop: wave tile = 128 rows x 64 cols ----
  const int q  = l >> 4;
  const int cl = l & 15;
  const int rbase = wv * 128;
  f32x4 acc[8][4] = {};

#pragma unroll 1
  for (int s = 0; s < 16; ++s) {
    const int k0 = s * 32 + q * 8;
    short8 a[8], b[4];
#pragma unroll
    for (int ct = 0; ct < 4; ++ct) {
      int c = ct * 16 + cl;
      int G = c * 64 + ((k0 >> 3) ^ (c & 7));
      b[ct] = *reinterpret_cast<const short8*>(&Bs[G * 8]);
    }
#pragma unroll
    for (int rt = 0; rt < 8; ++rt) {
      int row = rbase + rt * 16 + cl;
      a[rt] = *reinterpret_cast<const short8*>(eb + (size_t)row * KD + k0);
    }
#pragma unroll
    for (int rt = 0; rt < 8; ++rt)
#pragma unroll
      for (int ct = 0; ct < 4; ++ct)
        acc[rt][ct] = __builtin_amdgcn_mfma_f32_16x16x32_bf16(a[rt], b[ct], acc[rt][ct], 0, 0, 0);
  }

  // ---- epilogue: colnorm + transform + per-row partial sums (no atomics) ----
  const float t = tval[0];
#pragma unroll 1
  for (int rt = 0; rt < 8; ++rt) {
#pragma unroll
    for (int rg = 0; rg < 4; ++rg) {
      const int row = rbase + rt * 16 + q * 4 + rg;
      const float ctm = ctmA[row];
      const float fin = finA[row];
      const int   lab = label[row];
      float se = 0.f, sl = 0.f;
#pragma unroll
      for (int ct = 0; ct < 4; ++ct) {
        const int cg = c0 + ct * 16 + cl;
        if (cg < NCLS) {
          float cosv = acc[rt][ct][rg] * invnS[ct * 16 + cl];
          cosv = fminf(1.f, fmaxf(-1.f, cosv));
          float logit = (cosv > ctm) ? cosv * (t + cosv) : cosv;
          if (cg == lab) logit = fin;
          float x = S_SCALE * logit;
          se += __expf(x);
          sl += x;
        }
      }
#pragma unroll
      for (int m = 1; m < 16; m <<= 1) {
        se += __shfl_xor(se, m, 64);
        sl += __shfl_xor(sl, m, 64);
      }
      if (cl == 0) {
        partE[(size_t)row * NBPAD + blockIdx.x] = se;
        partL[(size_t)row * NBPAD + blockIdx.x] = sl;
      }
    }
  }
}

// ---- K3: per-row reduce over blocks + final loss (one atomic per row) ------
__global__ void k_reduce(const float* __restrict__ partE, const float* __restrict__ partL,
                         const float* __restrict__ finA, float* __restrict__ out) {
  const int r = blockIdx.x;
  const int tid = threadIdx.x;         // 256
  float se = 0.f, sl = 0.f;
  for (int i = tid; i < NB; i += 256) {
    se += partE[(size_t)r * NBPAD + i];
    sl += partL[(size_t)r * NBPAD + i];
  }
#pragma unroll
  for (int m = 1; m < 64; m <<= 1) {
    se += __shfl_xor(se, m, 64);
    sl += __shfl_xor(sl, m, 64);
  }
  __shared__ float rE[4], rL[4];
  if ((tid & 63) == 0) { rE[tid >> 6] = se; rL[tid >> 6] = sl; }
  __syncthreads();
  if (tid == 0) {
    float P = rE[0] + rE[1] + rE[2] + rE[3];
    float Q = rL[0] + rL[1] + rL[2] + rL[3];
    float lse = logf(P);               // no max-shift: P < 1e34
    float nll = lse - S_SCALE * finA[r];
    float sm  = lse - Q * (1.f / (float)NCLS);
    atomicAdd(out, (0.9f * nll + 0.1f * sm) * (1.f / 512.f));
  }
}

extern "C" void kernel_launch(void* const* d_in, const int* in_sizes, int n_in,
                              void* d_out, int out_size, void* d_ws, size_t ws_size,
                              hipStream_t stream) {
  (void)in_sizes; (void)n_in; (void)out_size; (void)ws_size;
  const float* emb = (const float*)d_in[0];
  const float* w   = (const float*)d_in[1];
  const int*   lab = (const int*)d_in[2];
  float* out = (float*)d_out;

  char* ws = (char*)d_ws;
  unsigned short* eb = (unsigned short*)ws;                       // 512 KB
  float* tlA   = (float*)(ws + 524288);
  float* ctmA  = tlA  + 512;
  float* finA  = ctmA + 512;
  float* tval  = finA + 512;
  float* partE = (float*)(ws + 524288 + 8192);                    // 512*1600 f32
  float* partL = partE + 512 * NBPAD;

  hipLaunchKernelGGL(k0_norm_target, dim3(512), dim3(64), 0, stream, emb, w, lab, eb, tlA);
  hipLaunchKernelGGL(k_prep,   dim3(1),   dim3(512), 0, stream, tlA, ctmA, finA, tval, out);
  hipLaunchKernelGGL(k_gemm,   dim3(NB),  dim3(256), 0, stream,
                     w, eb, lab, ctmA, finA, tval, partE, partL);
  hipLaunchKernelGGL(k_reduce, dim3(512), dim3(256), 0, stream, partE, partL, finA, out);
}